// Round 11
// baseline (249.785 us; speedup 1.0000x reference)
//
#include <hip/hip_runtime.h>

// Problem constants (match reference setup_inputs)
constexpr int D     = 128;            // D_IN == D_OUT
constexpr int R1    = 17;             // NUM_REL + 1
constexpr int BATCH = 16384;
constexpr int S     = 32;             // NUM_SAMPLE
constexpr int K     = R1 * D;         // 2176 (GEMM K dim)
constexpr int KB    = K / 8;          // 272 k-blocks of 8
constexpr int NPB   = 16;             // nodes per group
constexpr int NGRP  = 4;              // groups per block
constexpr int ASH   = K + 8;          // agg row stride in shorts (4368 B)
constexpr int THREADS = 1024;         // 16 waves, all gathering
constexpr int GRID  = BATCH / (NPB * NGRP);   // 256 blocks = 1/CU (persistent)
constexpr int NSTEP = K / 32;         // 68 MFMA steps
constexpr int QSTEP = NSTEP / 4;      // 17 per quarter

typedef __attribute__((ext_vector_type(8))) short short8;  // bf16x8 MFMA fragment
typedef __attribute__((ext_vector_type(4))) float f32x4;   // MFMA accumulator

__device__ __forceinline__ unsigned short f2bf_u(float f) {
    union { float f; unsigned u; } c; c.f = f;
    unsigned u = c.u;
    u += 0x7fffu + ((u >> 16) & 1u);
    return (unsigned short)(u >> 16);
}
__device__ __forceinline__ unsigned pack2bf(float lo, float hi) {
    return (unsigned)f2bf_u(lo) | ((unsigned)f2bf_u(hi) << 16);
}

// Pack W[17][128][128] (r,o,i) f32 -> Bp bf16 in B-fragment order:
// Bp[ot][kb][o][j]  where o_global = ot*16+o, k = kb*8+j, k = r*128+i.
__global__ void pack_w_kernel(const float* __restrict__ W, short* __restrict__ Bp) {
    int tid = blockIdx.x * 256 + threadIdx.x;
    if (tid >= R1 * D * D) return;
    int og = tid / K;
    int k  = tid - og * K;
    int r = k >> 7, i = k & 127;
    float v = W[((size_t)r * D + og) * D + i];
    int ot = og >> 4, o = og & 15, kb = k >> 3, j = k & 7;
    Bp[(((size_t)ot * KB + kb) * 16 + o) * 8 + j] = (short)f2bf_u(v);
}

// wave-uniform relation rr_ -> scalar branch cascade (R7 lesson: params not named x/y)
#define ACC_SWITCH(rr_, vv_)                                          \
    switch (rr_) {                                                    \
        case 0:  a0.x  += vv_.x; a0.y  += vv_.y; break;               \
        case 1:  a1.x  += vv_.x; a1.y  += vv_.y; break;               \
        case 2:  a2.x  += vv_.x; a2.y  += vv_.y; break;               \
        case 3:  a3.x  += vv_.x; a3.y  += vv_.y; break;               \
        case 4:  a4.x  += vv_.x; a4.y  += vv_.y; break;               \
        case 5:  a5.x  += vv_.x; a5.y  += vv_.y; break;               \
        case 6:  a6.x  += vv_.x; a6.y  += vv_.y; break;               \
        case 7:  a7.x  += vv_.x; a7.y  += vv_.y; break;               \
        case 8:  a8.x  += vv_.x; a8.y  += vv_.y; break;               \
        case 9:  a9.x  += vv_.x; a9.y  += vv_.y; break;               \
        case 10: a10.x += vv_.x; a10.y += vv_.y; break;               \
        case 11: a11.x += vv_.x; a11.y += vv_.y; break;               \
        case 12: a12.x += vv_.x; a12.y += vv_.y; break;               \
        case 13: a13.x += vv_.x; a13.y += vv_.y; break;               \
        case 14: a14.x += vv_.x; a14.y += vv_.y; break;               \
        case 15: a15.x += vv_.x; a15.y += vv_.y; break;               \
        default: a16.x += vv_.x; a16.y += vv_.y; break;               \
    }

#define LOAD8(buf, myreg, sbase)                                                \
    { _Pragma("unroll") for (int j = 0; j < 8; ++j) {                           \
        const int idx_ = __builtin_amdgcn_readlane(myreg, (sbase) + j);         \
        buf[j] = *reinterpret_cast<const float2*>(                              \
            embed + (size_t)idx_ * D + 2 * lane); } }

#define ACC8(myreg, sbase, buf)                                                 \
    { _Pragma("unroll") for (int j = 0; j < 8; ++j) {                           \
        const int rsel_ = __builtin_amdgcn_readlane(myreg, 32 + (sbase) + j);   \
        const float2 vsel_ = buf[j];                                            \
        ACC_SWITCH(rsel_, vsel_) } }

#define ZERO_ACC()                                                              \
    a0={0,0};a1={0,0};a2={0,0};a3={0,0};a4={0,0};a5={0,0};a6={0,0};a7={0,0};    \
    a8={0,0};a9={0,0};a10={0,0};a11={0,0};a12={0,0};a13={0,0};a14={0,0};        \
    a15={0,0};a16={0,0};

#define STORE_ACCP(ptr)                                                         \
    { unsigned* arow_ = reinterpret_cast<unsigned*>(ptr) + lane;                \
      arow_[0*64]=pack2bf(a0.x,a0.y);   arow_[1*64]=pack2bf(a1.x,a1.y);         \
      arow_[2*64]=pack2bf(a2.x,a2.y);   arow_[3*64]=pack2bf(a3.x,a3.y);         \
      arow_[4*64]=pack2bf(a4.x,a4.y);   arow_[5*64]=pack2bf(a5.x,a5.y);         \
      arow_[6*64]=pack2bf(a6.x,a6.y);   arow_[7*64]=pack2bf(a7.x,a7.y);         \
      arow_[8*64]=pack2bf(a8.x,a8.y);   arow_[9*64]=pack2bf(a9.x,a9.y);         \
      arow_[10*64]=pack2bf(a10.x,a10.y);arow_[11*64]=pack2bf(a11.x,a11.y);      \
      arow_[12*64]=pack2bf(a12.x,a12.y);arow_[13*64]=pack2bf(a13.x,a13.y);      \
      arow_[14*64]=pack2bf(a14.x,a14.y);arow_[15*64]=pack2bf(a15.x,a15.y);      \
      arow_[16*64]=pack2bf(a16.x,a16.y); }

// 17 MFMA steps of the col-tile GEMM (quarter q_); uses ar, bb, acc from scope
#define GEMM17(q_)                                                              \
    { _Pragma("unroll") for (int s = (q_)*QSTEP; s < (q_)*QSTEP + QSTEP; ++s) { \
        const short8 afrag_ = *reinterpret_cast<const short8*>(ar + s * 32);    \
        const short8 bfrag_ = *reinterpret_cast<const short8*>(bb + (size_t)s * 512); \
        acc = __builtin_amdgcn_mfma_f32_16x16x32_bf16(afrag_, bfrag_, acc, 0, 0, 0); } }

__device__ __forceinline__ int load_ids(const int* __restrict__ nbrs,
                                        const int* __restrict__ rels,
                                        int gn, int lane) {
    return (lane < 32) ? nbrs[(size_t)gn * S + lane]
                       : rels[(size_t)gn * S + (lane - 32)];
}

// R4's proven gather schedule for one node (ids already in `my`), LDS row `rowp`
__device__ __forceinline__ void gather_full(const float* __restrict__ embed,
                                            int my, int lane, short* rowp) {
    float2 a0={0,0},a1={0,0},a2={0,0},a3={0,0},a4={0,0},a5={0,0},
           a6={0,0},a7={0,0},a8={0,0},a9={0,0},a10={0,0},a11={0,0},
           a12={0,0},a13={0,0},a14={0,0},a15={0,0},a16={0,0};
    #pragma unroll 1
    for (int c = 0; c < 2; ++c) {
        const int sbase = c * 16;
        float2 v[16];
        #pragma unroll
        for (int j = 0; j < 16; ++j) {
            const int idx = __builtin_amdgcn_readlane(my, sbase + j);
            v[j] = *reinterpret_cast<const float2*>(embed + (size_t)idx * D + 2 * lane);
        }
        #pragma unroll
        for (int j = 0; j < 16; ++j) {
            const int r = __builtin_amdgcn_readlane(my, 32 + sbase + j);
            const float2 vx = v[j];
            ACC_SWITCH(r, vx)
        }
    }
    STORE_ACCP(rowp)
}

// Persistent fused kernel: per group, ALL 16 waves gather one node each (group
// g+1) while waves 0..7 also run the group-g GEMM, interleaved in the same
// instruction stream (GEMM17 quarters between gather chunks). 1 block/CU.
__global__ __launch_bounds__(THREADS, 4)
void rgcn_kernel(const float* __restrict__ embed,   // [1e6][128] f32
                 const short* __restrict__ Bp,      // packed bf16 weights (d_ws)
                 const int*   __restrict__ nbrs,    // [16384][32]
                 const int*   __restrict__ rels,    // [16384][32]
                 float* __restrict__ out)           // [16384][128]
{
    __shared__ short At[2][NPB][ASH];               // 2*16*2184*2 = 139,776 B

    const int t     = threadIdx.x;
    const int lane  = t & 63;
    const int w     = t >> 6;                       // wave 0..15 -> node w of each group
    const int base0 = blockIdx.x * NGRP * NPB;

    // prologue: gather group 0 into buf 0 (all 16 waves), prefetch group-1 ids
    {
        const int id0 = load_ids(nbrs, rels, base0 + w, lane);
        // fallthrough prefetch below issues together with this gather's loads
        gather_full(embed, id0, lane, &At[0][w][0]);
    }
    int my = load_ids(nbrs, rels, base0 + NPB + w, lane);   // ids for group 1
    __syncthreads();

    const float sc = 1000.0f / (float)(S * R1);

    #pragma unroll 1
    for (int g = 0; g < NGRP; ++g) {
        const int buf   = g & 1;
        const int gbase = base0 + g * NPB;

        if (w < 8) {
            // ---- gemm for group g (col-tile w), gather for group g+1 woven in ----
            const int m   = lane & 15;
            const int kb4 = lane >> 4;
            const short* ar = &At[buf][m][kb4 * 8];
            const short* bb = Bp + (((size_t)w * KB + kb4) * 16 + m) * 8;
            f32x4 acc = {0.f, 0.f, 0.f, 0.f};

            if (g < NGRP - 1) {
                int my2 = 0;
                if (g < NGRP - 2)
                    my2 = load_ids(nbrs, rels, base0 + (g + 2) * NPB + w, lane);
                float2 a0,a1,a2,a3,a4,a5,a6,a7,a8,a9,a10,a11,a12,a13,a14,a15,a16;
                ZERO_ACC();
                float2 vA[8], vB[8];
                GEMM17(0) LOAD8(vA, my, 0)
                GEMM17(1) LOAD8(vB, my, 8)  ACC8(my, 0,  vA)
                GEMM17(2) LOAD8(vA, my, 16) ACC8(my, 8,  vB)
                GEMM17(3) LOAD8(vB, my, 24) ACC8(my, 16, vA)
                ACC8(my, 24, vB)
                STORE_ACCP(&At[buf ^ 1][w][0])
                my = my2;
            } else {
                GEMM17(0) GEMM17(1) GEMM17(2) GEMM17(3)
            }

            #pragma unroll
            for (int j = 0; j < 4; ++j) {            // C/D: row = kb4*4+j, col = m
                out[(size_t)(gbase + kb4 * 4 + j) * D + w * 16 + m] =
                    fmaxf(acc[j] * sc, 0.0f);
            }
        } else {
            // ---- pure gather wave: node w of group g+1 ----
            if (g < NGRP - 1) {
                int my2 = 0;
                if (g < NGRP - 2)
                    my2 = load_ids(nbrs, rels, base0 + (g + 2) * NPB + w, lane);
                gather_full(embed, my, lane, &At[buf ^ 1][w][0]);
                my = my2;
            }
        }

        if (g < NGRP - 1) __syncthreads();
    }
}

extern "C" void kernel_launch(void* const* d_in, const int* in_sizes, int n_in,
                              void* d_out, int out_size, void* d_ws, size_t ws_size,
                              hipStream_t stream) {
    const float* embed = (const float*)d_in[0];
    const float* W     = (const float*)d_in[1];
    const int*   nbrs  = (const int*)d_in[2];
    const int*   rels  = (const int*)d_in[3];
    float* out = (float*)d_out;
    short* Bp  = (short*)d_ws;   // 557,056 B of scratch for packed W

    hipLaunchKernelGGL(pack_w_kernel, dim3((R1 * D * D + 255) / 256), dim3(256), 0, stream,
                       W, Bp);
    hipLaunchKernelGGL(rgcn_kernel, dim3(GRID), dim3(THREADS), 0, stream,
                       embed, Bp, nbrs, rels, out);
}

// Round 12
// 111.753 us; speedup vs baseline: 2.2352x; 2.2352x over previous
//
#include <hip/hip_runtime.h>

// Problem constants (match reference setup_inputs)
constexpr int D     = 128;            // D_IN == D_OUT
constexpr int R1    = 17;             // NUM_REL + 1
constexpr int BATCH = 16384;
constexpr int S     = 32;             // NUM_SAMPLE
constexpr int K     = R1 * D;         // 2176 (GEMM K dim)
constexpr int KB    = K / 8;          // 272 k-blocks of 8
constexpr int NPB   = 16;             // nodes (M rows) per block
constexpr int AS    = K + 8;          // agg row stride in shorts (4368 B, 16B-aligned)
constexpr int THREADS = 512;          // 8 waves

typedef __attribute__((ext_vector_type(8))) short short8;  // bf16x8 MFMA fragment
typedef __attribute__((ext_vector_type(4))) float f32x4;   // MFMA accumulator

__device__ __forceinline__ unsigned short f2bf_u(float f) {
    union { float f; unsigned u; } c; c.f = f;
    unsigned u = c.u;
    u += 0x7fffu + ((u >> 16) & 1u);
    return (unsigned short)(u >> 16);
}
__device__ __forceinline__ unsigned pack2bf(float lo, float hi) {
    return (unsigned)f2bf_u(lo) | ((unsigned)f2bf_u(hi) << 16);
}

// Pack W[17][128][128] (r,o,i) f32 -> Bp bf16 in B-fragment order:
// Bp[ot][kb][o][j]  where o_global = ot*16+o, k = kb*8+j, k = r*128+i.
__global__ void pack_w_kernel(const float* __restrict__ W, short* __restrict__ Bp) {
    int tid = blockIdx.x * 256 + threadIdx.x;
    if (tid >= R1 * D * D) return;
    int og = tid / K;
    int k  = tid - og * K;
    int r = k >> 7, i = k & 127;
    float v = W[((size_t)r * D + og) * D + i];
    int ot = og >> 4, o = og & 15, kb = k >> 3, j = k & 7;
    Bp[(((size_t)ot * KB + kb) * 16 + o) * 8 + j] = (short)f2bf_u(v);
}

// wave-uniform relation rr_ -> scalar branch cascade (params must not be x/y — R7 lesson)
#define ACC_SWITCH(rr_, vv_)                                          \
    switch (rr_) {                                                    \
        case 0:  a0.x  += vv_.x; a0.y  += vv_.y; break;               \
        case 1:  a1.x  += vv_.x; a1.y  += vv_.y; break;               \
        case 2:  a2.x  += vv_.x; a2.y  += vv_.y; break;               \
        case 3:  a3.x  += vv_.x; a3.y  += vv_.y; break;               \
        case 4:  a4.x  += vv_.x; a4.y  += vv_.y; break;               \
        case 5:  a5.x  += vv_.x; a5.y  += vv_.y; break;               \
        case 6:  a6.x  += vv_.x; a6.y  += vv_.y; break;               \
        case 7:  a7.x  += vv_.x; a7.y  += vv_.y; break;               \
        case 8:  a8.x  += vv_.x; a8.y  += vv_.y; break;               \
        case 9:  a9.x  += vv_.x; a9.y  += vv_.y; break;               \
        case 10: a10.x += vv_.x; a10.y += vv_.y; break;               \
        case 11: a11.x += vv_.x; a11.y += vv_.y; break;               \
        case 12: a12.x += vv_.x; a12.y += vv_.y; break;               \
        case 13: a13.x += vv_.x; a13.y += vv_.y; break;               \
        case 14: a14.x += vv_.x; a14.y += vv_.y; break;               \
        case 15: a15.x += vv_.x; a15.y += vv_.y; break;               \
        default: a16.x += vv_.x; a16.y += vv_.y; break;               \
    }

// issue 16 coalesced float2 row-loads for samples [sbase, sbase+16)
#define LOAD16(buf, myreg, sbase)                                               \
    { _Pragma("unroll") for (int j = 0; j < 16; ++j) {                          \
        const int idx_ = __builtin_amdgcn_readlane(myreg, (sbase) + j);         \
        buf[j] = *reinterpret_cast<const float2*>(                              \
            embed + (size_t)idx_ * D + 2 * lane); } }

// accumulate 16 samples from buf
#define ACC16(myreg, sbase, buf)                                                \
    { _Pragma("unroll") for (int j = 0; j < 16; ++j) {                          \
        const int rsel_ = __builtin_amdgcn_readlane(myreg, 32 + (sbase) + j);   \
        const float2 vsel_ = buf[j];                                            \
        ACC_SWITCH(rsel_, vsel_) } }

__global__ __launch_bounds__(THREADS, 4)   // 4 waves/EU -> 2 blocks/CU; VGPR cap 128
void rgcn_kernel(const float* __restrict__ embed,   // [1e6][128] f32
                 const short* __restrict__ Bp,      // packed bf16 weights (d_ws)
                 const int*   __restrict__ nbrs,    // [16384][32]
                 const int*   __restrict__ rels,    // [16384][32]
                 float* __restrict__ out)           // [16384][128]
{
    __shared__ short At[NPB][AS];                   // 16*4368 = 69,888 B -> 2 blocks/CU

    const int t     = threadIdx.x;
    const int lane  = t & 63;
    const int w     = t >> 6;                       // wave 0..7
    const int node0 = blockIdx.x * NPB;

    // ---------------- phase 1: gather + register accumulate, 32 loads in flight ---------
    // wave w owns nodes 2w, 2w+1 (serial, unroll 1 to bound register lifetimes);
    // lane owns dims {2*lane, 2*lane+1} -> one full 512B embed row per wave-load.
    #pragma unroll 1
    for (int p = 0; p < 2; ++p) {
        const int gn = node0 + 2 * w + p;
        // one coalesced load: lanes 0..31 = neighbor ids, lanes 32..63 = relation ids
        int my;
        if (lane < 32) my = nbrs[(size_t)gn * S + lane];
        else           my = rels[(size_t)gn * S + (lane - 32)];

        float2 a0={0,0},a1={0,0},a2={0,0},a3={0,0},a4={0,0},a5={0,0},
               a6={0,0},a7={0,0},a8={0,0},a9={0,0},a10={0,0},a11={0,0},
               a12={0,0},a13={0,0},a14={0,0},a15={0,0},a16={0,0};

        // all 32 gather loads issued before any consumption (32-deep concurrency)
        float2 v1[16], v2[16];
        LOAD16(v1, my, 0)
        LOAD16(v2, my, 16)
        ACC16 (my, 0,  v1)
        ACC16 (my, 16, v2)

        // packed bf16x2 LDS stores: dword index = r*64 + lane (conflict-free)
        unsigned* arow = reinterpret_cast<unsigned*>(&At[2 * w + p][0]) + lane;
        arow[0*64]  = pack2bf(a0.x,  a0.y);   arow[1*64]  = pack2bf(a1.x,  a1.y);
        arow[2*64]  = pack2bf(a2.x,  a2.y);   arow[3*64]  = pack2bf(a3.x,  a3.y);
        arow[4*64]  = pack2bf(a4.x,  a4.y);   arow[5*64]  = pack2bf(a5.x,  a5.y);
        arow[6*64]  = pack2bf(a6.x,  a6.y);   arow[7*64]  = pack2bf(a7.x,  a7.y);
        arow[8*64]  = pack2bf(a8.x,  a8.y);   arow[9*64]  = pack2bf(a9.x,  a9.y);
        arow[10*64] = pack2bf(a10.x, a10.y);  arow[11*64] = pack2bf(a11.x, a11.y);
        arow[12*64] = pack2bf(a12.x, a12.y);  arow[13*64] = pack2bf(a13.x, a13.y);
        arow[14*64] = pack2bf(a14.x, a14.y);  arow[15*64] = pack2bf(a15.x, a15.y);
        arow[16*64] = pack2bf(a16.x, a16.y);
    }
    __syncthreads();

    // ---------------- phase 2: C[16 x 128] = At[16 x 2176] @ Bp (bf16 MFMA) -------------
    // wave w owns output col-tile [w*16, w*16+16). B streamed non-temporally (no
    // L1 reuse within a block -> keep L1 for the other co-resident block's gather).
    {
        const int m   = lane & 15;      // A row within m-tile / output col within tile
        const int kb4 = lane >> 4;      // k-subblock 0..3

        f32x4 acc = {0.f, 0.f, 0.f, 0.f};

        const short* ar = &At[m][kb4 * 8];
        const short8* bb = reinterpret_cast<const short8*>(
            Bp + (((size_t)w * KB + kb4) * 16 + m) * 8);

        #pragma unroll 4
        for (int step = 0; step < K / 32; ++step) {
            const short8 a = *reinterpret_cast<const short8*>(ar + step * 32);
            const short8 b = __builtin_nontemporal_load(bb + step * 64);  // 64 short8 = 512 sh
            acc = __builtin_amdgcn_mfma_f32_16x16x32_bf16(a, b, acc, 0, 0, 0);
        }

        const float sc = 1000.0f / (float)(S * R1);
        #pragma unroll
        for (int j = 0; j < 4; ++j) {            // C/D: row = kb4*4+j, col = m
            __builtin_nontemporal_store(
                fmaxf(acc[j] * sc, 0.0f),
                out + (size_t)(node0 + kb4 * 4 + j) * D + w * 16 + m);
        }
    }
}

extern "C" void kernel_launch(void* const* d_in, const int* in_sizes, int n_in,
                              void* d_out, int out_size, void* d_ws, size_t ws_size,
                              hipStream_t stream) {
    const float* embed = (const float*)d_in[0];
    const float* W     = (const float*)d_in[1];
    const int*   nbrs  = (const int*)d_in[2];
    const int*   rels  = (const int*)d_in[3];
    float* out = (float*)d_out;
    short* Bp  = (short*)d_ws;   // 557,056 B of scratch for packed W

    hipLaunchKernelGGL(pack_w_kernel, dim3((R1 * D * D + 255) / 256), dim3(256), 0, stream,
                       W, Bp);
    hipLaunchKernelGGL(rgcn_kernel, dim3(BATCH / NPB), dim3(THREADS), 0, stream,
                       embed, Bp, nbrs, rels, out);
}